// Round 1
// baseline (166.990 us; speedup 1.0000x reference)
//
#include <hip/hip_runtime.h>

// DialogueGCN on MI355X.
// N=4096 utterances, D=512, window W=10 (WIN=21), S=8 speakers.
// Pipeline:
//   prep:  x -> split-bf16 A_att [N][1536]; w_att -> B_att^T [512][1536];
//          (w_gc|w_aggr) -> Wcat^T [2560][512] bf16 (x2 layers)
//   y = x @ w_att           (split-bf16 MFMA GEMM, K=1536, fp32 out)
//   scores/softmax          (fp32, banded, pads included in softmax)
//   hw = h @ Wcat           (bf16 MFMA GEMM, N=2560, bf16 out)
//   agg: banded weighted sum of 2 relation panels + aggr, relu
//   repeat for layer 2 -> d_out fp32

#define NN 4096
#define DD 512

typedef __bf16 bf16x8 __attribute__((ext_vector_type(8)));
typedef float f32x4 __attribute__((ext_vector_type(4)));
typedef unsigned short u16;

__device__ __forceinline__ u16 f2bf(float f) {
  unsigned u = __float_as_uint(f);
  unsigned r = u + 0x7FFFu + ((u >> 16) & 1u);
  return (u16)(r >> 16);
}
__device__ __forceinline__ float bf2f(u16 h) {
  return __uint_as_float(((unsigned)h) << 16);
}

__device__ __forceinline__ void gload_lds16(const u16* g, u16* l) {
  __builtin_amdgcn_global_load_lds(
      (const __attribute__((address_space(1))) void*)g,
      (__attribute__((address_space(3))) void*)l, 16, 0, 0);
}

// ---------------- prep kernels ----------------

// A_att[n][0:512)=hi(x), [512:1024)=lo(x), [1024:1536)=hi(x)
__global__ void prep_att_A(const float* __restrict__ x, u16* __restrict__ Aatt) {
  int idx = blockIdx.x * 256 + threadIdx.x;  // over N*512
  int r = idx >> 9, c = idx & 511;
  float v = x[idx];
  u16 hi = f2bf(v);
  u16 lo = f2bf(v - bf2f(hi));
  u16* row = Aatt + (size_t)r * 1536;
  row[c] = hi;
  row[512 + c] = lo;
  row[1024 + c] = hi;
}

// B_att^T[j][0:512)=hi(w_att[:,j]), [512:1024)=hi, [1024:1536)=lo
__global__ void prep_att_B(const float* __restrict__ w_att, u16* __restrict__ Bt) {
  int idx = blockIdx.x * 256 + threadIdx.x;  // over 512*512
  int j = idx >> 9, e = idx & 511;
  float v = w_att[(size_t)e * 512 + j];  // w_att[e][d=j]
  u16 hi = f2bf(v);
  u16 lo = f2bf(v - bf2f(hi));
  u16* row = Bt + (size_t)j * 1536;
  row[e] = hi;
  row[512 + e] = hi;
  row[1024 + e] = lo;
}

// Wcat^T [2560 j][512 k]: j<2048 -> w_gc[r=j>>9][k][e=j&511]; j>=2048 -> w_aggr[k][j-2048]
__global__ void prep_wcat(const float* __restrict__ w_gc, const float* __restrict__ w_aggr,
                          u16* __restrict__ Wt) {
  int idx = blockIdx.x * 256 + threadIdx.x;  // over 2560*512
  int j = idx >> 9, k = idx & 511;
  float v;
  if (j < 2048) {
    int r = j >> 9, e = j & 511;
    v = w_gc[((size_t)r * 512 + k) * 512 + e];
  } else {
    v = w_aggr[(size_t)k * 512 + (j - 2048)];
  }
  Wt[(size_t)j * 512 + k] = f2bf(v);
}

// ---------------- GEMM: C[M][N] = A[M][K] * Bt[N][K]^T ----------------
// 128x128 tile, BK=32, 4 waves (2x2), 16x16x32 bf16 MFMA, global_load_lds staging.

template <int OUT_BF16>
__global__ __launch_bounds__(256, 2) void gemm_bt(const u16* __restrict__ A,
                                                  const u16* __restrict__ Bt,
                                                  void* __restrict__ C, int K, int lda,
                                                  int ldb, int ldc) {
  __shared__ u16 As[128 * 32];
  __shared__ u16 Bs[128 * 32];
  const int tid = threadIdx.x;
  const int lane = tid & 63;
  const int wave = tid >> 6;
  const int wr = wave >> 1, wc = wave & 1;
  const size_t bm = (size_t)blockIdx.y * 128;
  const size_t bn = (size_t)blockIdx.x * 128;

  f32x4 acc[4][4] = {};

  const int i0 = tid * 8;        // staging element index, round 0
  const int i1 = i0 + 2048;      // round 1
  const int ar0 = i0 >> 5, ac0 = i0 & 31;
  const int ar1 = i1 >> 5, ac1 = i1 & 31;

  const int kb = (lane >> 4) * 8;
  const int arow = wr * 64 + (lane & 15);
  const int bcol = wc * 64 + (lane & 15);

  for (int k0 = 0; k0 < K; k0 += 32) {
    gload_lds16(A + (bm + ar0) * lda + k0 + ac0, &As[i0]);
    gload_lds16(A + (bm + ar1) * lda + k0 + ac1, &As[i1]);
    gload_lds16(Bt + (bn + ar0) * ldb + k0 + ac0, &Bs[i0]);
    gload_lds16(Bt + (bn + ar1) * ldb + k0 + ac1, &Bs[i1]);
    asm volatile("s_waitcnt vmcnt(0)" ::: "memory");
    __syncthreads();

    bf16x8 af[4], bfr[4];
#pragma unroll
    for (int i = 0; i < 4; ++i) {
      af[i] = *(const bf16x8*)&As[(arow + i * 16) * 32 + kb];
      bfr[i] = *(const bf16x8*)&Bs[(bcol + i * 16) * 32 + kb];
    }
#pragma unroll
    for (int i = 0; i < 4; ++i)
#pragma unroll
      for (int j = 0; j < 4; ++j)
        acc[i][j] = __builtin_amdgcn_mfma_f32_16x16x32_bf16(af[i], bfr[j], acc[i][j], 0, 0, 0);
    __syncthreads();
  }

  // C/D layout (verified m89): col = lane&15, row = (lane>>4)*4 + b
  const size_t crow = bm + wr * 64 + ((lane >> 4) * 4);
  const size_t ccol = bn + wc * 64 + (lane & 15);
#pragma unroll
  for (int i = 0; i < 4; ++i)
#pragma unroll
    for (int j = 0; j < 4; ++j)
#pragma unroll
      for (int b = 0; b < 4; ++b) {
        size_t r = crow + i * 16 + b, c = ccol + j * 16;
        if (OUT_BF16)
          ((u16*)C)[r * ldc + c] = f2bf(acc[i][j][b]);
        else
          ((float*)C)[r * ldc + c] = acc[i][j][b];
      }
}

// ---------------- scores + softmax ----------------
// scores[n][w] = dot(x[n+w-10], y[n]) (0 if out of range, still in softmax)
__global__ void attn_scores(const float* __restrict__ x, const float* __restrict__ y,
                            float* __restrict__ attn) {
  const int row = blockIdx.x;
  __shared__ float ys[512];
  __shared__ float sc[21];
  const int tid = threadIdx.x;  // 256
  for (int i = tid; i < 512; i += 256) ys[i] = y[(size_t)row * 512 + i];
  __syncthreads();
  const int wave = tid >> 6, lane = tid & 63;
  for (int w = wave; w < 21; w += 4) {
    int m = row + w - 10;
    float s = 0.f;
    if (0 <= m && m < NN) {
      const float* xm = x + (size_t)m * 512;
      float p = 0.f;
#pragma unroll
      for (int i = 0; i < 8; ++i) p += xm[lane + i * 64] * ys[lane + i * 64];
#pragma unroll
      for (int off = 32; off; off >>= 1) p += __shfl_xor(p, off, 64);
      s = p;
    }
    if (lane == 0) sc[w] = s;
  }
  __syncthreads();
  if (tid < 64) {
    float v = (tid < 21) ? sc[tid] : -1e30f;
    float mx = v;
#pragma unroll
    for (int off = 32; off; off >>= 1) mx = fmaxf(mx, __shfl_xor(mx, off, 64));
    float e = (tid < 21) ? __expf(v - mx) : 0.f;
    float sum = e;
#pragma unroll
    for (int off = 32; off; off >>= 1) sum += __shfl_xor(sum, off, 64);
    if (tid < 21) {
      int m = row + tid - 10;
      attn[(size_t)row * 24 + tid] = (0 <= m && m < NN) ? (e / sum) : 0.f;
    }
  }
}

// ---------------- banded aggregation + relu ----------------
// agg[n][e] = hw[n][2048+e] + sum_w attn[n][w]*(hw[m][t*512+e] + hw[m][s*512+e])
template <bool OUT_BF16>
__global__ void aggregate(const u16* __restrict__ hw, const float* __restrict__ attn,
                          const int* __restrict__ spk, void* __restrict__ out) {
  const int row = blockIdx.x;
  const int tid = threadIdx.x;  // 256 threads, 2 cols each
  const int e0 = tid, e1 = tid + 256;
  const int myspk = spk[row];
  const u16* hrow = hw + (size_t)row * 2560;
  float a0 = bf2f(hrow[2048 + e0]);
  float a1 = bf2f(hrow[2048 + e1]);
  for (int w = 0; w < 21; ++w) {
    int m = row + w - 10;
    if (m < 0 || m >= NN) continue;
    float a = attn[(size_t)row * 24 + w];
    const u16* hm = hw + (size_t)m * 2560;
    int t = (m >= row) ? 0 : 1;             // pred : suc
    int s = (spk[m] == myspk) ? 2 : 3;      // same : diff
    a0 += a * (bf2f(hm[t * 512 + e0]) + bf2f(hm[s * 512 + e0]));
    a1 += a * (bf2f(hm[t * 512 + e1]) + bf2f(hm[s * 512 + e1]));
  }
  a0 = fmaxf(a0, 0.f);
  a1 = fmaxf(a1, 0.f);
  if (OUT_BF16) {
    u16* o = (u16*)out + (size_t)row * 512;
    o[e0] = f2bf(a0);
    o[e1] = f2bf(a1);
  } else {
    float* o = (float*)out + (size_t)row * 512;
    o[e0] = a0;
    o[e1] = a1;
  }
}

// ---------------- launch ----------------

extern "C" void kernel_launch(void* const* d_in, const int* in_sizes, int n_in,
                              void* d_out, int out_size, void* d_ws, size_t ws_size,
                              hipStream_t stream) {
  const float* x = (const float*)d_in[0];
  const int* spk = (const int*)d_in[1];
  const float* w_gc1 = (const float*)d_in[2];
  const float* w_gc2 = (const float*)d_in[3];
  const float* w_att = (const float*)d_in[4];
  const float* w_aggr1 = (const float*)d_in[5];
  const float* w_aggr2 = (const float*)d_in[6];

  char* p = (char*)d_ws;
  u16* Aatt = (u16*)p;  p += (size_t)NN * 1536 * 2;   // 12.6 MB
  u16* Batt = (u16*)p;  p += (size_t)512 * 1536 * 2;  // 1.6 MB
  u16* Wt1 = (u16*)p;   p += (size_t)2560 * 512 * 2;  // 2.6 MB
  u16* Wt2 = (u16*)p;   p += (size_t)2560 * 512 * 2;  // 2.6 MB
  float* y = (float*)p; p += (size_t)NN * 512 * 4;    // 8.4 MB
  float* attn = (float*)p; p += (size_t)NN * 24 * 4;  // 0.4 MB
  u16* hw = (u16*)p;    p += (size_t)NN * 2560 * 2;   // 21.0 MB
  u16* h1 = (u16*)p;    p += (size_t)NN * 512 * 2;    // 4.2 MB  (~53.3 MB total)

  prep_att_A<<<NN * 512 / 256, 256, 0, stream>>>(x, Aatt);
  prep_att_B<<<512 * 512 / 256, 256, 0, stream>>>(w_att, Batt);
  prep_wcat<<<2560 * 512 / 256, 256, 0, stream>>>(w_gc1, w_aggr1, Wt1);
  prep_wcat<<<2560 * 512 / 256, 256, 0, stream>>>(w_gc2, w_aggr2, Wt2);

  // y = x @ w_att, split-bf16 (fp32-accurate), M=4096 N=512 K=1536
  gemm_bt<0><<<dim3(512 / 128, NN / 128), 256, 0, stream>>>(Aatt, Batt, y, 1536, 1536, 1536, 512);

  attn_scores<<<NN, 256, 0, stream>>>(x, y, attn);

  // layer 1: hw = x_bf16 @ Wcat1  (A = hi block of Aatt, lda=1536)
  gemm_bt<1><<<dim3(2560 / 128, NN / 128), 256, 0, stream>>>(Aatt, Wt1, hw, 512, 1536, 512, 2560);
  aggregate<true><<<NN, 256, 0, stream>>>(hw, attn, spk, h1);

  // layer 2
  gemm_bt<1><<<dim3(2560 / 128, NN / 128), 256, 0, stream>>>(h1, Wt2, hw, 512, 512, 512, 2560);
  aggregate<false><<<NN, 256, 0, stream>>>(hw, attn, spk, d_out);
}

// Round 2
// 146.897 us; speedup vs baseline: 1.1368x; 1.1368x over previous
//
#include <hip/hip_runtime.h>

// DialogueGCN on MI355X — round 1.
// Restructured: agg[n] = z_pred@(W0-W1) + z_same@(W2-W3) + z_all@(W1+W3) + h@W_aggr
// Per layer: banded gather (z_pred|z_same|z_all|h -> Z [N][2048] bf16), then one
// GEMM Z @ Wmix^T -> h (relu). 64x64-tile GEMM => 512 blocks (2/CU) for all GEMMs.

#define NN 4096
#define DD 512

typedef __bf16 bf16x8 __attribute__((ext_vector_type(8)));
typedef float f32x4 __attribute__((ext_vector_type(4)));
typedef unsigned short u16;
typedef unsigned int u32;

__device__ __forceinline__ u16 f2bf(float f) {
  unsigned u = __float_as_uint(f);
  unsigned r = u + 0x7FFFu + ((u >> 16) & 1u);
  return (u16)(r >> 16);
}
__device__ __forceinline__ float bf2f(u16 h) {
  return __uint_as_float(((unsigned)h) << 16);
}
__device__ __forceinline__ u32 packbf(float a, float b) {
  return (u32)f2bf(a) | ((u32)f2bf(b) << 16);
}

__device__ __forceinline__ void gload_lds16(const u16* g, u16* l) {
  __builtin_amdgcn_global_load_lds(
      (const __attribute__((address_space(1))) void*)g,
      (__attribute__((address_space(3))) void*)l, 16, 0, 0);
}

// ---------------- fused prep ----------------
// seg A (blocks [0,8192)):    x -> Aatt [N][1536] = [hi | lo | hi]
// seg B (blocks [8192,9216)): w_att -> Batt [512][1536] = [hi | hi | lo] of w_att[:,j]
// seg W (blocks [9216,17408)): Wmix^T [512 j][2048 k] for layers 1,2:
//   k panel 0: gc0-gc1, 1: gc2-gc3, 2: gc1+gc3, 3: w_aggr   (all [kk][j] indexed)
__global__ void prep_all(const float* __restrict__ x, const float* __restrict__ w_att,
                         const float* __restrict__ w_gc1, const float* __restrict__ w_aggr1,
                         const float* __restrict__ w_gc2, const float* __restrict__ w_aggr2,
                         u16* __restrict__ Aatt, u16* __restrict__ Batt,
                         u16* __restrict__ Wt1, u16* __restrict__ Wt2) {
  const int b = blockIdx.x, tid = threadIdx.x;
  if (b < 8192) {
    int idx = b * 256 + tid;
    int r = idx >> 9, c = idx & 511;
    float v = x[idx];
    u16 hi = f2bf(v), lo = f2bf(v - bf2f(hi));
    u16* row = Aatt + (size_t)r * 1536;
    row[c] = hi; row[512 + c] = lo; row[1024 + c] = hi;
  } else if (b < 9216) {
    int idx = (b - 8192) * 256 + tid;
    int j = idx >> 9, e = idx & 511;
    float v = w_att[(size_t)e * 512 + j];
    u16 hi = f2bf(v), lo = f2bf(v - bf2f(hi));
    u16* row = Batt + (size_t)j * 1536;
    row[e] = hi; row[512 + e] = hi; row[1024 + e] = lo;
  } else {
    int lay = (b >= 13312);
    int idx = (b - (lay ? 13312 : 9216)) * 256 + tid;
    const float* g = lay ? w_gc2 : w_gc1;
    const float* wa = lay ? w_aggr2 : w_aggr1;
    u16* Wt = lay ? Wt2 : Wt1;
    int j = idx >> 11, k = idx & 2047;
    int p = k >> 9, kk = k & 511;
    size_t o = (size_t)kk * 512 + j;
    float v;
    if (p == 0)      v = g[o] - g[262144 + o];
    else if (p == 1) v = g[524288 + o] - g[786432 + o];
    else if (p == 2) v = g[262144 + o] + g[786432 + o];
    else             v = wa[o];
    Wt[(size_t)j * 2048 + k] = f2bf(v);
  }
}

// ---------------- GEMM: C[M][N] = A[M][K] * Bt[N][K]^T ----------------
// 64x64 tile, BK=32, 4 waves (2x2, wave tile 32x32), double-buffered LDS,
// stage(t+1)-before-compute(t). MODE: 0=f32 raw, 1=bf16 relu, 2=f32 relu.
template <int MODE>
__global__ __launch_bounds__(256, 4) void gemm64(const u16* __restrict__ A,
                                                 const u16* __restrict__ Bt,
                                                 void* __restrict__ C, int K, int lda,
                                                 int ldb, int ldc) {
  __shared__ u16 As[2][64 * 32];
  __shared__ u16 Bs[2][64 * 32];
  const int tid = threadIdx.x;
  const int lane = tid & 63;
  const int wave = tid >> 6;
  const int wr = wave >> 1, wc = wave & 1;
  const size_t bm = (size_t)blockIdx.y * 64;
  const size_t bn = (size_t)blockIdx.x * 64;

  const int srow = tid >> 2, scol = (tid & 3) * 8;  // staging: 64 rows x 32 cols
  const int kb = (lane >> 4) * 8;
  const int arow = wr * 32 + (lane & 15);
  const int bcol = wc * 32 + (lane & 15);

  f32x4 acc[2][2] = {};

  const int nt = K >> 5;
  int cur = 0;
  gload_lds16(A + (bm + srow) * lda + scol, &As[0][tid * 8]);
  gload_lds16(Bt + (bn + srow) * ldb + scol, &Bs[0][tid * 8]);
  __syncthreads();

  for (int t = 0; t < nt; ++t) {
    if (t + 1 < nt) {
      int k0 = (t + 1) << 5;
      gload_lds16(A + (bm + srow) * lda + k0 + scol, &As[cur ^ 1][tid * 8]);
      gload_lds16(Bt + (bn + srow) * ldb + k0 + scol, &Bs[cur ^ 1][tid * 8]);
    }
    bf16x8 af[2], bfr[2];
#pragma unroll
    for (int i = 0; i < 2; ++i) {
      af[i] = *(const bf16x8*)&As[cur][(arow + i * 16) * 32 + kb];
      bfr[i] = *(const bf16x8*)&Bs[cur][(bcol + i * 16) * 32 + kb];
    }
#pragma unroll
    for (int i = 0; i < 2; ++i)
#pragma unroll
      for (int j = 0; j < 2; ++j)
        acc[i][j] = __builtin_amdgcn_mfma_f32_16x16x32_bf16(af[i], bfr[j], acc[i][j], 0, 0, 0);
    __syncthreads();
    cur ^= 1;
  }

  const size_t crow = bm + wr * 32 + ((lane >> 4) * 4);
  const size_t ccol = bn + wc * 32 + (lane & 15);
#pragma unroll
  for (int i = 0; i < 2; ++i)
#pragma unroll
    for (int j = 0; j < 2; ++j)
#pragma unroll
      for (int b = 0; b < 4; ++b) {
        size_t r = crow + i * 16 + b, c = ccol + j * 16;
        if (MODE == 0)
          ((float*)C)[r * ldc + c] = acc[i][j][b];
        else if (MODE == 1)
          ((u16*)C)[r * ldc + c] = f2bf(fmaxf(acc[i][j][b], 0.f));
        else
          ((float*)C)[r * ldc + c] = fmaxf(acc[i][j][b], 0.f);
      }
}

// ---------------- fused scores + softmax + gather (layer 1) ----------------
// scores[n][w] = x[n+w-10] . y[n] (0 if out of range, kept in softmax).
// Then z_pred/z_same/z_all banded sums over fp32 x; Z[n] = [zp|zs|za|bf16(x[n])].
__global__ void gather1(const float* __restrict__ x, const float* __restrict__ y,
                        const int* __restrict__ spk, float* __restrict__ attn,
                        u16* __restrict__ Z) {
  const int n = blockIdx.x, tid = threadIdx.x;
  __shared__ float ys[512];
  __shared__ float sc[21];
  __shared__ float av[21];
  __shared__ int sps[21];
  ys[tid] = y[(size_t)n * 512 + tid];
  ys[tid + 256] = y[(size_t)n * 512 + tid + 256];
  if (tid < 21) {
    int m = n + tid - 10;
    sps[tid] = (0 <= m && m < NN) ? spk[m] : -1;
  }
  __syncthreads();
  const int wave = tid >> 6, lane = tid & 63;
  for (int w = wave; w < 21; w += 4) {
    int m = n + w - 10;
    float s = 0.f;
    if (0 <= m && m < NN) {
      const float* xm = x + (size_t)m * 512;
      float p = 0.f;
#pragma unroll
      for (int i = 0; i < 8; ++i) p += xm[lane + i * 64] * ys[lane + i * 64];
#pragma unroll
      for (int off = 32; off; off >>= 1) p += __shfl_xor(p, off, 64);
      s = p;
    }
    if (lane == 0) sc[w] = s;
  }
  __syncthreads();
  if (tid < 64) {
    float v = (tid < 21) ? sc[tid] : -1e30f;
    float mx = v;
#pragma unroll
    for (int off = 32; off; off >>= 1) mx = fmaxf(mx, __shfl_xor(mx, off, 64));
    float e = (tid < 21) ? __expf(v - mx) : 0.f;
    float sum = e;
#pragma unroll
    for (int off = 32; off; off >>= 1) sum += __shfl_xor(sum, off, 64);
    if (tid < 21) {
      int m = n + tid - 10;
      float a = (0 <= m && m < NN) ? (e / sum) : 0.f;
      av[tid] = a;
      attn[(size_t)n * 24 + tid] = a;
    }
  }
  __syncthreads();
  const int c0 = tid * 2;
  const int mysp = spk[n];
  float zp0 = 0, zp1 = 0, zs0 = 0, zs1 = 0, za0 = 0, za1 = 0;
  for (int w = 0; w < 21; ++w) {
    int m = n + w - 10;
    if (m < 0 || m >= NN) continue;
    float a = av[w];
    const float* xm = x + (size_t)m * 512 + c0;
    float v0 = xm[0], v1 = xm[1];
    za0 += a * v0; za1 += a * v1;
    if (m >= n) { zp0 += a * v0; zp1 += a * v1; }
    if (sps[w] == mysp) { zs0 += a * v0; zs1 += a * v1; }
  }
  u32* zr = (u32*)(Z + (size_t)n * 2048);
  zr[tid] = packbf(zp0, zp1);
  zr[256 + tid] = packbf(zs0, zs1);
  zr[512 + tid] = packbf(za0, za1);
  const float* xn = x + (size_t)n * 512 + c0;
  zr[768 + tid] = packbf(xn[0], xn[1]);
}

// ---------------- gather (layer 2): h1 bf16 -> Z ----------------
__global__ void gather2(const u16* __restrict__ h, const float* __restrict__ attn,
                        const int* __restrict__ spk, u16* __restrict__ Z) {
  const int n = blockIdx.x, tid = threadIdx.x;
  __shared__ float av[21];
  __shared__ int sps[21];
  if (tid < 21) {
    int m = n + tid - 10;
    av[tid] = attn[(size_t)n * 24 + tid];
    sps[tid] = (0 <= m && m < NN) ? spk[m] : -1;
  }
  __syncthreads();
  const int c0 = tid * 2;
  const int mysp = spk[n];
  float zp0 = 0, zp1 = 0, zs0 = 0, zs1 = 0, za0 = 0, za1 = 0;
  for (int w = 0; w < 21; ++w) {
    int m = n + w - 10;
    if (m < 0 || m >= NN) continue;
    float a = av[w];
    u32 hv = *(const u32*)(h + (size_t)m * 512 + c0);
    float v0 = bf2f((u16)hv), v1 = bf2f((u16)(hv >> 16));
    za0 += a * v0; za1 += a * v1;
    if (m >= n) { zp0 += a * v0; zp1 += a * v1; }
    if (sps[w] == mysp) { zs0 += a * v0; zs1 += a * v1; }
  }
  u32* zr = (u32*)(Z + (size_t)n * 2048);
  zr[tid] = packbf(zp0, zp1);
  zr[256 + tid] = packbf(zs0, zs1);
  zr[512 + tid] = packbf(za0, za1);
  zr[768 + tid] = *(const u32*)(h + (size_t)n * 512 + c0);
}

// ---------------- launch ----------------
extern "C" void kernel_launch(void* const* d_in, const int* in_sizes, int n_in,
                              void* d_out, int out_size, void* d_ws, size_t ws_size,
                              hipStream_t stream) {
  const float* x = (const float*)d_in[0];
  const int* spk = (const int*)d_in[1];
  const float* w_gc1 = (const float*)d_in[2];
  const float* w_gc2 = (const float*)d_in[3];
  const float* w_att = (const float*)d_in[4];
  const float* w_aggr1 = (const float*)d_in[5];
  const float* w_aggr2 = (const float*)d_in[6];

  char* p = (char*)d_ws;
  u16* Aatt = (u16*)p;  p += (size_t)NN * 1536 * 2;    // 12.6 MB
  u16* Batt = (u16*)p;  p += (size_t)512 * 1536 * 2;   // 1.6 MB
  u16* Wt1 = (u16*)p;   p += (size_t)512 * 2048 * 2;   // 2.1 MB
  u16* Wt2 = (u16*)p;   p += (size_t)512 * 2048 * 2;   // 2.1 MB
  float* y = (float*)p; p += (size_t)NN * 512 * 4;     // 8.4 MB
  float* attn = (float*)p; p += (size_t)NN * 24 * 4;   // 0.4 MB
  u16* Z = (u16*)p;     p += (size_t)NN * 2048 * 2;    // 16.8 MB
  u16* h1 = (u16*)p;    p += (size_t)NN * 512 * 2;     // 4.2 MB (~48 MB total)

  prep_all<<<17408, 256, 0, stream>>>(x, w_att, w_gc1, w_aggr1, w_gc2, w_aggr2,
                                      Aatt, Batt, Wt1, Wt2);

  // y = x @ w_att (split-bf16), M=4096 N=512 K=1536, fp32 out
  gemm64<0><<<dim3(8, 64), 256, 0, stream>>>(Aatt, Batt, y, 1536, 1536, 1536, 512);

  gather1<<<NN, 256, 0, stream>>>(x, y, spk, attn, Z);

  // h1 = relu(Z @ Wmix1), M=4096 N=512 K=2048, bf16 out
  gemm64<1><<<dim3(8, 64), 256, 0, stream>>>(Z, Wt1, h1, 2048, 2048, 2048, 512);

  gather2<<<NN, 256, 0, stream>>>(h1, attn, spk, Z);

  // out = relu(Z @ Wmix2), fp32
  gemm64<2><<<dim3(8, 64), 256, 0, stream>>>(Z, Wt2, d_out, 2048, 2048, 2048, 512);
}